// Round 5
// baseline (1105.067 us; speedup 1.0000x reference)
//
#include <hip/hip_runtime.h>
#include <math.h>

// ---------------- problem constants ----------------
#define POSE_ROWS 144
#define NF 135
#define DD 512
#define KQ 10
#define DCTN 34
#define INN 120
#define OUTN 24
#define VN 87
#define BATCH 256
#define RP 34816              // padded row dim: 256 * 136
#define NODEP 136
#define BN_SCALE 0.9999950000374997f

typedef __attribute__((ext_vector_type(8))) short short8;
typedef __attribute__((ext_vector_type(4))) float floatx4;

static __device__ __forceinline__ ushort f2bf(float f) {
    unsigned u = __builtin_bit_cast(unsigned, f);
    u = (u + 0x7FFFu + ((u >> 16) & 1u)) >> 16;
    return (ushort)u;
}
static __device__ __forceinline__ float bf2f(ushort s) {
    return __builtin_bit_cast(float, (unsigned)s << 16);
}
// fast tanh: tanh(|x|) = (1-e^{-2|x|})/(1+e^{-2|x|}), ~6 VALU vs ~28 for tanhf
static __device__ __forceinline__ float tanh_fast(float x) {
    float ax = __builtin_fabsf(x);
    float e = __builtin_amdgcn_exp2f(ax * -2.885390081777927f);   // e^{-2ax}
    float t = (1.f - e) * __builtin_amdgcn_rcpf(1.f + e);
    return __builtin_copysignf(t, x);
}

#define GLOAD_LDS(gp, lp) __builtin_amdgcn_global_load_lds( \
    (const __attribute__((address_space(1))) unsigned int*)(const void*)(gp), \
    (__attribute__((address_space(3))) unsigned int*)(void*)(lp), 16, 0, 0)

// ---------------- fused prep kernel (all weight repacks / converts in ONE dispatch) ----
#define PB_POSES 19584
#define PB_K1A   21248
#define PB_K1B   22912
#define PB_K2A   28032
#define PB_K2B   33152
#define PB_WT1   33408
#define PB_WTB   37504
#define PB_WT7   37640
#define PB_A1    37742
#define PB_AB    38147
#define PB_A7    38249
#define PB_BN    39609
#define PB_Z     39610
#define PB_DCT   39615

__global__ __launch_bounds__(256) void prep_all(
    const float* __restrict__ poses, ushort* __restrict__ pb16,
    const float* __restrict__ kw1, const float* __restrict__ qw1,
    ushort* __restrict__ Wt1k, ushort* __restrict__ Wt1q,
    const float* __restrict__ kw2, const float* __restrict__ qw2,
    ushort* __restrict__ Wt2k, ushort* __restrict__ Wt2q,
    const float* __restrict__ gc1_w, ushort* __restrict__ WT1,
    const float* __restrict__ gcb_w, ushort* __restrict__ WTb,
    const float* __restrict__ gc7_w, ushort* __restrict__ WT7,
    const float* __restrict__ gc1_att, ushort* __restrict__ A16_1,
    const float* __restrict__ gcb_att, ushort* __restrict__ A16_B,
    const float* __restrict__ gc7_att, ushort* __restrict__ A16_7,
    const float* __restrict__ bn1_g, const float* __restrict__ bn1_b,
    const float* __restrict__ gcb_g, const float* __restrict__ gcb_beta,
    float* __restrict__ bnT, float* __restrict__ zpadf, float* __restrict__ dct)
{
    const int blk = blockIdx.x;
    const int tid = threadIdx.x;
    if (blk < PB_POSES) {
        int idx = blk * 256 + tid;
        int i = idx % NODEP;
        int row = (idx / NODEP) % POSE_ROWS;
        int b = idx / (NODEP * POSE_ROWS);
        float v = (i < NF) ? poses[((long long)b * POSE_ROWS + row) * NF + i] * 1e-3f : 0.f;
        pb16[idx] = f2bf(v);
    } else if (blk < PB_K1B) {
        int wi = blk - PB_POSES;
        const float* src = (wi < 1664) ? kw1 : qw1;
        ushort* dst = (wi < 1664) ? Wt1k : Wt1q;
        int idx = (wi % 1664) * 256 + tid;
        int n = idx / 832, k = idx % 832;
        int h = k / 136, i = k % 136;
        float v = (i < 135 && h < 6) ? src[((long long)n * 135 + i) * 6 + h] : 0.f;
        dst[idx] = f2bf(v);
    } else if (blk < PB_K2B) {
        int wi = blk - PB_K1B;
        const float* src = (wi < 5120) ? kw2 : qw2;
        ushort* dst = (wi < 5120) ? Wt2k : Wt2q;
        int idx = (wi % 5120) * 256 + tid;
        int n = idx / 2560, k = idx % 2560;
        int h = k / 512, i = k % 512;
        dst[idx] = f2bf(src[((long long)n * 512 + i) * 5 + h]);
    } else if (blk < PB_WT1) {
        int idx = (blk - PB_K2B) * 256 + tid;
        int n = idx / 128, k = idx % 128;
        WT1[idx] = f2bf((k < 68) ? gc1_w[(long long)k * 512 + n] : 0.f);
    } else if (blk < PB_WTB) {
        int g = (blk - PB_WT1) * 256 + tid;
        int L = g >> 18, idx = g & 262143;
        int n = idx / 512, k = idx % 512;
        WTb[g] = f2bf(gcb_w[(long long)L * 262144 + (long long)k * 512 + n]);
    } else if (blk < PB_WT7) {
        int idx = (blk - PB_WTB) * 256 + tid;
        int n = idx / 512, k = idx % 512;
        WT7[idx] = f2bf(gc7_w[(long long)k * 68 + n]);
    } else if (blk < PB_A1) {
        int idx = (blk - PB_WT7) * 256 + tid;
        if (idx < 135 * 192) {
            int r = idx / 192, c = idx % 192;
            A16_1[idx] = f2bf(c < 135 ? gc1_att[r * 135 + c] : 0.f);
        }
    } else if (blk < PB_AB) {
        int idx = (blk - PB_A1) * 256 + tid;
        int r = idx / 192, c = idx % 192;
        A16_B[idx] = f2bf(c < 135 ? gcb_att[r * 135 + c] : 0.f);
    } else if (blk < PB_A7) {
        int idx = (blk - PB_AB) * 256 + tid;
        if (idx < 135 * 192) {
            int r = idx / 192, c = idx % 192;
            A16_7[idx] = f2bf(c < 135 ? gc7_att[r * 135 + c] : 0.f);
        }
    } else if (blk < PB_BN) {
        int g = (blk - PB_A7) * 256 + tid;
        int p = g / 69632, idx = g % 69632;
        int node = idx % 136, m = idx / 136;
        const float* gs = (p == 0) ? bn1_g : (gcb_g + (p - 1) * 69120);
        const float* bs = (p == 0) ? bn1_b : (gcb_beta + (p - 1) * 69120);
        float* gt = bnT + (long long)p * 139264;
        float* bt = gt + 69632;
        gt[idx] = (node < 135) ? gs[node * 512 + m] : 0.f;
        bt[idx] = (node < 135) ? bs[node * 512 + m] : 0.f;
    } else if (blk < PB_Z) {
        if (tid < 128) zpadf[tid] = 0.f;
    } else {
        int idx = (blk - PB_Z) * 256 + tid;
        if (idx < DCTN * DCTN) {
            int k = idx / DCTN, i = idx % DCTN;
            double w = (k == 0) ? sqrt(1.0 / DCTN) : sqrt(2.0 / DCTN);
            dct[idx] = (float)(w * cos(3.14159265358979323846 * (i + 0.5) * k / (double)DCTN));
        }
    }
}

// ---------------- NT MFMA GEMM, BK=64, global_load_lds staging, XOR-swizzled LDS ----------
template<int BM, int BN>
__global__ __launch_bounds__(256) void gemm2(
    const ushort* __restrict__ A, const ushort* __restrict__ Bt,
    const ushort* __restrict__ zpad,
    int M, int N, int K,
    int rpbA, long long sAw, long long sAr, long long sAbz,
    long long sBr, long long sBbz,
    float* __restrict__ C, ushort* __restrict__ C16,
    long long sCbz, long long sCm, long long sCn,
    int do_relu, const float* __restrict__ bias, int bias_mode,
    const float* __restrict__ bnTg, const float* __restrict__ bnTb,
    int do_tanh, const ushort* __restrict__ resid16, const float* __restrict__ resid32)
{
    constexpr int SM = BM / 32, SN = BN / 32;
    constexpr int RA = BM / 32, RB = BN / 32;     // staging rounds, 32 rows each
    __shared__ ushort As[BM * 64];
    __shared__ ushort Bs[BN * 64];

    const int tid = threadIdx.x;
    const int lane = tid & 63, w = tid >> 6;
    const int bz = blockIdx.z;
    const int m0 = blockIdx.y * BM, n0 = blockIdx.x * BN;
    const int wm = (w >> 1) * (BM / 2), wn = (w & 1) * (BN / 2);
    const int chunk = (lane & 7) ^ ((lane >> 3) & 7);

    const ushort* pA[RA]; int stA[RA];
    #pragma unroll
    for (int j = 0; j < RA; j++) {
        int m = m0 + j * 32 + w * 8 + (lane >> 3);
        bool v = m < M;
        long long off = v ? ((long long)(m / rpbA) * sAw + (long long)(m % rpbA) * sAr
                            + (long long)bz * sAbz) : 0;
        pA[j] = v ? (A + off + chunk * 8) : (zpad + chunk * 8);
        stA[j] = v ? 64 : 0;
    }
    const ushort* pB[RB]; int stB[RB];
    #pragma unroll
    for (int j = 0; j < RB; j++) {
        int n = n0 + j * 32 + w * 8 + (lane >> 3);
        bool v = n < N;
        long long off = v ? ((long long)n * sBr + (long long)bz * sBbz) : 0;
        pB[j] = v ? (Bt + off + chunk * 8) : (zpad + chunk * 8);
        stB[j] = v ? 64 : 0;
    }

    floatx4 acc[SM][SN];
    #pragma unroll
    for (int i = 0; i < SM; i++)
        #pragma unroll
        for (int j = 0; j < SN; j++)
            acc[i][j] = (floatx4){0.f, 0.f, 0.f, 0.f};

    for (int k0 = 0; k0 < K; k0 += 64) {
        #pragma unroll
        for (int j = 0; j < RA; j++)
            GLOAD_LDS(pA[j], &As[(j * 32 + w * 8) * 64]);
        #pragma unroll
        for (int j = 0; j < RB; j++)
            GLOAD_LDS(pB[j], &Bs[(j * 32 + w * 8) * 64]);
        __syncthreads();

        #pragma unroll
        for (int kk = 0; kk < 2; kk++) {
            short8 af[SM], bf[SN];
            #pragma unroll
            for (int sm = 0; sm < SM; sm++) {
                int lr = wm + sm * 16 + (lane & 15);
                int slot = ((lane >> 4) + kk * 4) ^ (lr & 7);
                af[sm] = *(const short8*)&As[lr * 64 + slot * 8];
            }
            #pragma unroll
            for (int sn = 0; sn < SN; sn++) {
                int lr = wn + sn * 16 + (lane & 15);
                int slot = ((lane >> 4) + kk * 4) ^ (lr & 7);
                bf[sn] = *(const short8*)&Bs[lr * 64 + slot * 8];
            }
            #pragma unroll
            for (int sm = 0; sm < SM; sm++)
                #pragma unroll
                for (int sn = 0; sn < SN; sn++)
                    acc[sm][sn] = __builtin_amdgcn_mfma_f32_16x16x32_bf16(af[sm], bf[sn], acc[sm][sn], 0, 0, 0);
        }
        __syncthreads();

        #pragma unroll
        for (int j = 0; j < RA; j++) pA[j] += stA[j];
        #pragma unroll
        for (int j = 0; j < RB; j++) pB[j] += stB[j];
    }

    // epilogue: D mapping col(n)=lane&15, row(m)=(lane>>4)*4+r
    const int lc = lane & 15;
    const int lr4 = (lane >> 4) << 2;
    #pragma unroll
    for (int sm = 0; sm < SM; sm++) {
        #pragma unroll
        for (int sn = 0; sn < SN; sn++) {
            int n = n0 + wn + sn * 16 + lc;
            if (n >= N) continue;
            int node = n % 136;
            int mb = m0 + wm + sm * 16 + lr4;
            float vv[4];
            #pragma unroll
            for (int r = 0; r < 4; r++) {
                int m = mb + r;
                float v = acc[sm][sn][r];
                if (do_relu) v = fmaxf(v, 0.f);
                if (bias) v += (bias_mode == 1) ? bias[m < M ? m : 0] : bias[n];
                if (bnTg) {
                    long long gi = (long long)(m < M ? m : 0) * 136 + node;
                    v = bnTg[gi] * (v * BN_SCALE) + bnTb[gi];
                }
                if (do_tanh) v = tanh_fast(v);
                long long addr = (long long)bz * sCbz + (long long)m * sCm + (long long)n * sCn;
                if (m < M) {
                    if (resid16) v += bf2f(resid16[addr]);
                    else if (resid32) v += resid32[addr];
                    if (C) C[addr] = v;
                    if (C16 && sCm != 1) C16[addr] = f2bf(v);
                }
                vv[r] = v;
            }
            if (C16 && sCm == 1 && mb + 3 < M) {
                ushort4 pk;
                pk.x = f2bf(vv[0]); pk.y = f2bf(vv[1]); pk.z = f2bf(vv[2]); pk.w = f2bf(vv[3]);
                *(ushort4*)&C16[(long long)bz * sCbz + mb + (long long)n * sCn] = pk;
            }
        }
    }
}

// ---------------- attention scores + normalize (wave-parallel) ----------------
__global__ __launch_bounds__(256) void att_k(const float* __restrict__ kf, const float* __restrict__ qf,
                                             float* __restrict__ att) {
    int b = blockIdx.x;
    int tid = threadIdx.x;
    int lane = tid & 63, w = tid >> 6;
    __shared__ float s[96];
    __shared__ float ssum;
    const float* qb = qf + b * DD + lane * 8;
    float4 q0 = *(const float4*)qb;
    float4 q1 = *(const float4*)(qb + 4);
    const float* kb = kf + (long long)b * VN * DD;
    for (int v = w; v < VN; v += 4) {
        const float* kr = kb + v * DD + lane * 8;
        float4 k0 = *(const float4*)kr;
        float4 k1 = *(const float4*)(kr + 4);
        float p = q0.x * k0.x + q0.y * k0.y + q0.z * k0.z + q0.w * k0.w
                + q1.x * k1.x + q1.y * k1.y + q1.z * k1.z + q1.w * k1.w;
        #pragma unroll
        for (int off = 32; off; off >>= 1) p += __shfl_xor(p, off);
        if (lane == 0) s[v] = p + 1e-15f;
    }
    __syncthreads();
    if (tid < 64) {
        float p2 = (tid < VN ? s[tid] : 0.f) + ((tid + 64) < VN ? s[tid + 64] : 0.f);
        #pragma unroll
        for (int off = 32; off; off >>= 1) p2 += __shfl_xor(p2, off);
        if (tid == 0) ssum = p2;
    }
    __syncthreads();
    float inv = 1.f / ssum;
    for (int v = tid; v < VN; v += 256) att[b * VN + v] = s[v] * inv;
}

// ---------------- w34[b,t,f] = sum_v att[b,v] * poses[b,v+t,f] ----------------
__global__ void weighted_k(const float* __restrict__ poses, const float* __restrict__ att,
                           float* __restrict__ w34) {
    int t = blockIdx.x;
    int b = blockIdx.y;
    int f = threadIdx.x;
    if (f >= NF) return;
    const float* pb = poses + (long long)b * POSE_ROWS * NF + t * NF + f;
    const float* ab = att + b * VN;
    float acc = 0.f;
    for (int v = 0; v < VN; v++) acc += ab[v] * pb[v * NF];
    w34[(long long)b * DCTN * NF + t * NF + f] = acc;
}

// ---------------- x = concat(dct_in, dct_att); node-major f32 + feature-major bf16 ----
__global__ void build_x(const float* __restrict__ poses, const float* __restrict__ w34,
                        const float* __restrict__ dctm, float* __restrict__ x32,
                        ushort* __restrict__ xT16) {
    int idx = blockIdx.x * 256 + threadIdx.x;
    if (idx >= BATCH * NF * 68) return;
    int kk = idx % 68;
    int f = (idx / 68) % NF;
    int b = idx / (68 * NF);
    float acc = 0.f;
    if (kk < DCTN) {
        const float* pb = poses + (long long)b * POSE_ROWS * NF;
        #pragma unroll
        for (int t = 0; t < DCTN; t++) {
            int row = (t < KQ) ? (INN - KQ + t) : (INN - 1);
            acc += dctm[kk * DCTN + t] * pb[row * NF + f];
        }
    } else {
        int k2 = kk - DCTN;
        const float* wb = w34 + (long long)b * DCTN * NF + f;
        #pragma unroll
        for (int t = 0; t < DCTN; t++) acc += dctm[k2 * DCTN + t] * wb[t * NF];
    }
    long long R = (long long)b * NODEP + f;
    x32[R * 68 + kk] = acc;
    xT16[(long long)kk * RP + R] = f2bf(acc);
}

// ---------------- preds[b,t,f] = sum_k dct[k][10+t] * h32[(b*136+f)*68+k] ----------------
__global__ void idct_out(const float* __restrict__ h32, const float* __restrict__ dctm,
                         float* __restrict__ out) {
    int idx = blockIdx.x * 256 + threadIdx.x;
    if (idx >= BATCH * OUTN * NF) return;
    int f = idx % NF;
    int t = (idx / NF) % OUTN;
    int b = idx / (NF * OUTN);
    const float* yr = h32 + ((long long)b * NODEP + f) * 68;
    float acc = 0.f;
    #pragma unroll
    for (int k = 0; k < DCTN; k++) acc += dctm[k * DCTN + (KQ + t)] * yr[k];
    out[idx] = acc;
}

// ---------------- host ----------------
extern "C" void kernel_launch(void* const* d_in, const int* in_sizes, int n_in,
                              void* d_out, int out_size, void* d_ws, size_t ws_size,
                              hipStream_t stream) {
    const float* poses   = (const float*)d_in[0];
    const float* qw1     = (const float*)d_in[1];
    const float* qw2     = (const float*)d_in[2];
    const float* kw1     = (const float*)d_in[3];
    const float* kw2     = (const float*)d_in[4];
    const float* gc1_att = (const float*)d_in[5];
    const float* gc1_w   = (const float*)d_in[6];
    const float* gc1_b   = (const float*)d_in[7];
    const float* bn1_g   = (const float*)d_in[8];
    const float* bn1_b   = (const float*)d_in[9];
    const float* gcb_att = (const float*)d_in[10];
    const float* gcb_w   = (const float*)d_in[11];
    const float* gcb_b   = (const float*)d_in[12];
    const float* gcb_g   = (const float*)d_in[13];
    const float* gcb_beta= (const float*)d_in[14];
    const float* gc7_att = (const float*)d_in[15];
    const float* gc7_w   = (const float*)d_in[16];
    const float* gc7_b   = (const float*)d_in[17];
    float* out = (float*)d_out;
    float* w = (float*)d_ws;

    // ---- workspace layout (f32 units) ----
    float* dct   = w;                      // 1156 -> pad 1280
    float* att   = w + 1280;               // -> 23808
    float* w34   = w + 23808;              // -> 1198848
    float* x32   = w + 1198848;            // RP*68 -> 3566336
    float* h32   = w + 3566336;            // RP*68 -> 5933824
    float* qf    = w + 5933824;            // -> 6064896
    ushort* su   = (ushort*)(w + 6064896); // bf16 weight region
    ushort* WT1    = su;                   // 512*128   = 65536
    ushort* WTb    = su + 65536;           // 4*512*512 = 1048576
    ushort* WT7    = su + 1114112;         // 68*512    = 34816
    ushort* A16_1  = su + 1148928;         // 135*192   = 25920
    ushort* A16_B  = su + 1174848;         // 540*192   = 103680
    ushort* A16_7  = su + 1278528;         // 25920
    float* bnT   = w + 6717120;            // 10 * 69632 -> 7413440
    float* kf    = w + 7413440;            // 256*87*512 -> 18816704
    ushort* R2   = (ushort*)(w + 18816704);
    ushort* yT16  = R2;
    ushort* r1k16 = R2;                    // phase-A alias
    ushort* r1q16 = R2 + 11927552;
    ushort* R3   = (ushort*)(w + 27729600);
    ushort* hT16  = R3;
    ushort* pb16  = R3;                    // phase-A alias
    ushort* Wt1k  = R3 + 5013504;
    ushort* Wt1q  = R3 + 5439488;
    ushort* Wt2k  = R3 + 5865472;
    ushort* Wt2q  = R3 + 7176192;
    ushort* R4   = (ushort*)(w + 36642496);
    ushort* zN16  = R4;
    ushort* xT16  = R4;                    // alias (dead before zN16 written)
    ushort* z116  = R4 + 2367488;          // RP*80
    float* zpadf = w + 45555392;           // 128 f zero page
    const ushort* zpad = (const ushort*)zpadf;

    const int INF_RPB = 1 << 30;

    // ---- fused prep (one dispatch) ----
    prep_all<<<PB_DCT, 256, 0, stream>>>(
        poses, pb16, kw1, qw1, Wt1k, Wt1q, kw2, qw2, Wt2k, Wt2q,
        gc1_w, WT1, gcb_w, WTb, gc7_w, WT7,
        gc1_att, A16_1, gcb_att, A16_B, gc7_att, A16_7,
        bn1_g, bn1_b, gcb_g, gcb_beta, bnT, zpadf, dct);

    // ---- conv stack (128x128 tiles: proven best L2/L3 reuse) ----
    gemm2<128,128><<<dim3(4, 182, 1), 256, 0, stream>>>(pb16, Wt1k, zpad, 23296, 512, 832,
        91, 19584LL, 136LL, 0LL, 832LL, 0LL,
        (float*)nullptr, r1k16, 0LL, 512LL, 1LL, 1, nullptr, 0, nullptr, nullptr, 0, nullptr, nullptr);
    gemm2<128,128><<<dim3(4, 10, 1), 256, 0, stream>>>(pb16 + 110*136, Wt1q, zpad, 1280, 512, 832,
        5, 19584LL, 136LL, 0LL, 832LL, 0LL,
        (float*)nullptr, r1q16, 0LL, 512LL, 1LL, 1, nullptr, 0, nullptr, nullptr, 0, nullptr, nullptr);
    gemm2<128,128><<<dim3(4, 174, 1), 256, 0, stream>>>(r1k16, Wt2k, zpad, 22272, 512, 2560,
        87, 46592LL, 512LL, 0LL, 2560LL, 0LL,
        kf, (ushort*)nullptr, 0LL, 512LL, 1LL, 1, nullptr, 0, nullptr, nullptr, 0, nullptr, nullptr);
    gemm2<64,64><<<dim3(8, 4, 1), 256, 0, stream>>>(r1q16, Wt2q, zpad, 256, 512, 2560,
        INF_RPB, 0LL, 2560LL, 0LL, 2560LL, 0LL,
        qf, (ushort*)nullptr, 0LL, 512LL, 1LL, 1, nullptr, 0, nullptr, nullptr, 0, nullptr, nullptr);

    // ---- attention + x ----
    att_k<<<BATCH, 256, 0, stream>>>(kf, qf, att);
    weighted_k<<<dim3(DCTN, BATCH), 192, 0, stream>>>(poses, att, w34);
    build_x<<<(BATCH * NF * 68 + 255) / 256, 256, 0, stream>>>(poses, w34, dct, x32, xT16);

    // ---- gc1: mix then W(68->512) ----
    gemm2<64,64><<<dim3(3, 2, BATCH), 256, 0, stream>>>(xT16, A16_1, zpad, 68, 135, 192,
        INF_RPB, 0LL, (long long)RP, 136LL, 192LL, 0LL,
        (float*)nullptr, z116, 10880LL, 1LL, 80LL, 0, nullptr, 0, nullptr, nullptr, 0, nullptr, nullptr);
    gemm2<128,128><<<dim3(272, 4, 1), 256, 0, stream>>>(WT1, z116, zpad, 512, RP, 128,
        INF_RPB, 0LL, 128LL, 0LL, 80LL, 0LL,
        (float*)nullptr, yT16, 0LL, (long long)RP, 1LL, 0, gc1_b, 1, bnT, bnT + 69632, 1, nullptr, nullptr);

    // ---- residual GCN blocks ----
    for (int L = 0; L < 4; L++) {
        const ushort* min = (L & 1) ? hT16 : yT16;
        gemm2<64,64><<<dim3(3, 8, BATCH), 256, 0, stream>>>(min, A16_B + L*25920, zpad, 512, 135, 192,
            INF_RPB, 0LL, (long long)RP, 136LL, 192LL, 0LL,
            (float*)nullptr, zN16, 69632LL, 1LL, 512LL, 0, nullptr, 0, nullptr, nullptr, 0, nullptr, nullptr);
        gemm2<128,128><<<dim3(272, 4, 1), 256, 0, stream>>>(WTb + L*262144, zN16, zpad, 512, RP, 512,
            INF_RPB, 0LL, 512LL, 0LL, 512LL, 0LL,
            (float*)nullptr, (L & 1) ? yT16 : hT16, 0LL, (long long)RP, 1LL,
            0, gcb_b + L*512, 1, bnT + (1 + L) * 139264, bnT + (1 + L) * 139264 + 69632, 1,
            (L & 1) ? yT16 : (const ushort*)nullptr, nullptr);
    }

    // ---- gc7: mix then W(512->68) + bias + x residual ----
    gemm2<64,64><<<dim3(3, 8, BATCH), 256, 0, stream>>>(yT16, A16_7, zpad, 512, 135, 192,
        INF_RPB, 0LL, (long long)RP, 136LL, 192LL, 0LL,
        (float*)nullptr, zN16, 69632LL, 1LL, 512LL, 0, nullptr, 0, nullptr, nullptr, 0, nullptr, nullptr);
    gemm2<64,64><<<dim3(2, 544, 1), 256, 0, stream>>>(zN16, WT7, zpad, RP, 68, 512,
        INF_RPB, 0LL, 512LL, 0LL, 512LL, 0LL,
        h32, (ushort*)nullptr, 0LL, 68LL, 1LL, 0, gc7_b, 2, nullptr, nullptr, 0, nullptr, x32);

    idct_out<<<(BATCH * OUTN * NF + 255) / 256, 256, 0, stream>>>(h32, dct, out);
}